// Round 16
// baseline (85.278 us; speedup 1.0000x reference)
//
#include <hip/hip_runtime.h>
#include <hip/hip_cooperative_groups.h>
#include <hip/hip_bf16.h>

#define N_IN    256
#define N_HID   128
#define N_ELEM  5
#define NBLK    512                 // mlp blocks; 2 per CU (65.5KB LDS each)
#define PREPB   256                 // coop prep blocks (1 per CU, co-resident)
#define ESTRIDE 66560               // per-expert image: 65536 frag + 1024 params

typedef __attribute__((ext_vector_type(8))) short  short8;
typedef __attribute__((ext_vector_type(4))) short  short4v;
typedef __attribute__((ext_vector_type(4))) float  float4v;

__device__ __forceinline__ int expert_of(int z) {
    return (z == 1) ? 0 : (z == 6) ? 1 : (z == 7) ? 2 : (z == 8) ? 3 : 4;
}
__device__ __forceinline__ short f2bf(float f) {
    union { float f; unsigned u; } c; c.f = f;
    unsigned r = (c.u + 0x7fffu + ((c.u >> 16) & 1u)) >> 16;
    return (short)r;
}

#define AS3 __attribute__((address_space(3)))
#define GLOAD_LDS16(gsrc, ldst) \
    __builtin_amdgcn_global_load_lds((const __attribute__((address_space(1))) void*)(gsrc), \
                                     (AS3 void*)(ldst), 16, 0, 0)
__device__ __forceinline__ unsigned lds_off(const void* p) {
    return (unsigned)(size_t)(AS3 const char*)p;
}

#define DSR128(dst, a) asm volatile("ds_read_b128 %0, %1" : "=v"(dst) : "v"(a))
#define LGKM0 do { asm volatile("s_waitcnt lgkmcnt(0)" ::: "memory"); \
                   __builtin_amdgcn_sched_barrier(0); } while (0)
#define WAITV0 do { asm volatile("s_waitcnt vmcnt(0)" ::: "memory"); \
                    __builtin_amdgcn_sched_barrier(0); } while (0)

// ---------------- cooperative prep: hist + W1s image + deterministic scatter ---
// Phase A: W1 fp32->bf16 swizzled image + params (gtid-strided, <=1 item/thread)
//          + per-block expert histogram of a register-held z chunk (4 atoms/thr).
// grid.sync()
// Phase B: atomic-free global exclusive prefix (thread t holds block t's counts;
//          wave-reduce totals and prefix-below-ourblock), then scatter from regs.
// z is read ONCE; no memset; no global atomics; fully deterministic output.
__global__ void coop_prep_kernel(const float* __restrict__ W1, const float* __restrict__ B1f,
                                 const float* __restrict__ W2f, char* __restrict__ W1s,
                                 const int* __restrict__ z, int n,
                                 int* __restrict__ blockCnt, int* __restrict__ counts,
                                 int* __restrict__ perm) {
    namespace cg = cooperative_groups;
    cg::grid_group grid = cg::this_grid();

    __shared__ int cntL[N_ELEM];
    __shared__ int baseL[N_ELEM];
    __shared__ int redT[4][N_ELEM], redP[4][N_ELEM];

    int tid  = threadIdx.x;
    int b    = blockIdx.x;
    int gtid = b * 256 + tid;                // 0 .. 65535
    int w    = tid >> 6, lane = tid & 63;

    if (tid < N_ELEM) cntL[tid] = 0;
    __syncthreads();

    // ---- phase A1: W1s frag image + params (21760 items over 65536 threads)
    if (gtid < 20480) {
        int e = gtid >> 12, rem = gtid & 4095;
        int slot = rem >> 6, ln = rem & 63;
        int nrow = (slot >> 3) * 16 + (ln & 15);
        int k0 = (slot & 7) * 32 + (ln >> 4) * 8;
        const float* src = W1 + ((size_t)(e * N_HID + nrow) * N_IN + k0);
        float4v f0 = *(const float4v*)src;
        float4v f1 = *(const float4v*)(src + 4);
        short8 s;
        s[0] = f2bf(f0[0]); s[1] = f2bf(f0[1]); s[2] = f2bf(f0[2]); s[3] = f2bf(f0[3]);
        s[4] = f2bf(f1[0]); s[5] = f2bf(f1[1]); s[6] = f2bf(f1[2]); s[7] = f2bf(f1[3]);
        *(short8*)(W1s + (size_t)e * ESTRIDE + slot * 1024 + ln * 16) = s;
    } else if (gtid < 21760) {
        int idx2 = gtid - 20480;             // < 1280
        int e = idx2 >> 8, i = idx2 & 255;
        float* dst = (float*)(W1s + (size_t)e * ESTRIDE + 65536);
        if (i < 128) dst[i] = B1f[e * N_HID + i];
        else         dst[128 + (i - 128)] = W2f[e * N_HID + (i - 128)];
    }

    // ---- phase A2: register-held z chunk + per-block histogram
    int eR[4], rR[4], aR[4];
#pragma unroll
    for (int k = 0; k < 4; ++k) {
        int a = gtid + k * 65536;
        aR[k] = a; eR[k] = -1; rR[k] = 0;
        if (a < n) {
            eR[k] = expert_of(z[a]);
            rR[k] = atomicAdd(&cntL[eR[k]], 1);   // LDS: rank within (block,e)
        }
    }
    __syncthreads();
    if (tid < N_ELEM) blockCnt[b * N_ELEM + tid] = cntL[tid];

    grid.sync();

    // ---- phase B1: atomic-free exclusive prefix (thread t <-> block t)
    int v[N_ELEM];
#pragma unroll
    for (int e = 0; e < N_ELEM; ++e) v[e] = blockCnt[tid * N_ELEM + e];
    int fl = (tid < b) ? 1 : 0;
#pragma unroll
    for (int e = 0; e < N_ELEM; ++e) {
        int s = v[e], p = fl ? v[e] : 0;
#pragma unroll
        for (int sh = 1; sh <= 32; sh <<= 1) {
            s += __shfl_xor(s, sh, 64);
            p += __shfl_xor(p, sh, 64);
        }
        if (lane == 0) { redT[w][e] = s; redP[w][e] = p; }
    }
    __syncthreads();
    if (tid == 0) {
        int seg = 0;
#pragma unroll
        for (int e = 0; e < N_ELEM; ++e) {
            int tot = redT[0][e] + redT[1][e] + redT[2][e] + redT[3][e];
            int pre = redP[0][e] + redP[1][e] + redP[2][e] + redP[3][e];
            baseL[e] = seg + pre;
            if (b == 0) counts[e] = tot;
            seg += tot;
        }
    }
    __syncthreads();

    // ---- phase B2: scatter from registers
#pragma unroll
    for (int k = 0; k < 4; ++k)
        if (eR[k] >= 0) perm[baseL[eR[k]] + rR[k]] = aR[k];
}

// ---------------- mlp: expert-uniform blocks, shared 64KB B, interleaved pipe --
// (byte-identical to R15's passing 72.0us kernel)
__launch_bounds__(256, 2)
__global__ void mlp_kernel(const float* __restrict__ X, const char* __restrict__ W1s,
                           const float* __restrict__ B2f, const int* __restrict__ perm,
                           const int* __restrict__ counts, float* __restrict__ out) {
    __shared__ char Bs[65536];              // one expert's full fragment image

    int lane = threadIdx.x & 63;
    int w    = threadIdx.x >> 6;
    int am   = lane & 15, g = lane >> 4;

    int cntv[N_ELEM], so[N_ELEM], ns[N_ELEM];
    int nSub = 0, acc0 = 0;
#pragma unroll
    for (int e = 0; e < N_ELEM; ++e) {
        cntv[e] = counts[e];
        so[e] = acc0; acc0 += cntv[e];
        ns[e] = (cntv[e] + 15) >> 4;
        nSub += ns[e];
    }
    int blk[N_ELEM], tot = 0;
#pragma unroll
    for (int e = 0; e < N_ELEM; ++e) {
        blk[e] = (int)(((long long)NBLK * ns[e]) / nSub);
        tot += blk[e];
    }
    int rem = NBLK - tot;
#pragma unroll
    for (int e = 0; e < N_ELEM; ++e)
        if (rem > 0 && ns[e] > 0) { blk[e]++; rem--; }
    while (rem > 0) { blk[0]++; rem--; }
#pragma unroll
    for (int e = 0; e < N_ELEM; ++e)
        if (ns[e] > 0 && blk[e] == 0) {
            int m = 0;
            for (int j = 1; j < N_ELEM; ++j) if (blk[j] > blk[m]) m = j;
            blk[m]--; blk[e]++;
        }
    int bp1 = blk[0], bp2 = bp1 + blk[1], bp3 = bp2 + blk[2], bp4 = bp3 + blk[3];

    int b = blockIdx.x;
    int e = (b >= bp1) + (b >= bp2) + (b >= bp3) + (b >= bp4);
    int bloc = b - ((e == 0) ? 0 : (e == 1) ? bp1 : (e == 2) ? bp2 : (e == 3) ? bp3 : bp4);
    int BE = blk[e], NE = ns[e];
    int soE = so[e], ctE = cntv[e];

    const char* img = W1s + (size_t)e * ESTRIDE;
    {
        const char* wsrc = img + w * 16384 + lane * 16;
        char* wdst = Bs + w * 16384;
#pragma unroll
        for (int i = 0; i < 16; ++i)
            GLOAD_LDS16(wsrc + i * 1024, wdst + i * 1024);
    }
    WAITV0;
    __syncthreads();

    int qe = (BE > 0) ? NE / BE : 0, re = (BE > 0) ? NE % BE : 0;
    int tb0 = bloc * qe + min(bloc, re);
    int tb1 = tb0 + qe + (bloc < re ? 1 : 0);
    int L = tb1 - tb0;
    int qw = L >> 2, rw = L & 3;
    int s0 = tb0 + w * qw + min(w, rw);
    int s1 = s0 + qw + (w < rw ? 1 : 0);
    if (s0 >= s1) return;

    unsigned BOFF = lds_off(Bs);
    int lastA = soE + ctE - 1;

    const float* prm = (const float*)(img + 65536);
    float b1c[8], w2c[8];
#pragma unroll
    for (int n = 0; n < 8; ++n) {
        b1c[n] = prm[n * 16 + am];
        w2c[n] = prm[128 + n * 16 + am];
    }
    float b2v = B2f[e];

#define ROWSOF(s_) min(16, ctE - (s_) * 16)
#define GIDOF(s_) perm[min(soE + (s_) * 16 + am, lastA)]

    int rowsC = ROWSOF(s0);
    int gidC = GIDOF(s0);
    float4v rawA[16];
    {
        const float* base0 = X + ((size_t)(unsigned)gidC << 8) + g * 8;
#pragma unroll
        for (int kk = 0; kk < 8; ++kk) {
            rawA[2 * kk]     = *(const float4v*)(base0 + kk * 32);
            rawA[2 * kk + 1] = *(const float4v*)(base0 + kk * 32 + 4);
        }
    }
    int rowsN = rowsC, gidN = gidC;
    if (s0 + 1 < s1) { rowsN = ROWSOF(s0 + 1); gidN = GIDOF(s0 + 1); }

    for (int s = s0; s < s1; ++s) {
        bool pf = (s + 1 < s1);
        const float* baseN = X + ((size_t)(unsigned)gidN << 8) + g * 8;

        float4v acc[8] = {};
#pragma unroll
        for (int kk = 0; kk < 8; ++kk) {
            short8 bpre[8];
#pragma unroll
            for (int n = 0; n < 8; ++n)
                DSR128(bpre[n], BOFF + (unsigned)((n * 8 + kk) * 1024 + lane * 16));
            short8 abf;
            {
                float4v f0 = rawA[2 * kk], f1 = rawA[2 * kk + 1];
                union { __hip_bfloat162 h[4]; short8 v; } u;
                u.h[0] = __float22bfloat162_rn({f0[0], f0[1]});
                u.h[1] = __float22bfloat162_rn({f0[2], f0[3]});
                u.h[2] = __float22bfloat162_rn({f1[0], f1[1]});
                u.h[3] = __float22bfloat162_rn({f1[2], f1[3]});
                abf = u.v;
            }
            if (pf) {
                rawA[2 * kk]     = *(const float4v*)(baseN + kk * 32);
                rawA[2 * kk + 1] = *(const float4v*)(baseN + kk * 32 + 4);
            }
            LGKM0;
#pragma unroll
            for (int n = 0; n < 8; ++n)
                acc[n] = __builtin_amdgcn_mfma_f32_16x16x32_bf16(
                    abf, bpre[n], acc[n], 0, 0, 0);
        }

        float pv0 = 0, pv1 = 0, pv2 = 0, pv3 = 0;
#pragma unroll
        for (int n = 0; n < 8; ++n) {
            float v0 = acc[n][0] + b1c[n]; v0 = v0 / (1.0f + __expf(-v0));
            float v1 = acc[n][1] + b1c[n]; v1 = v1 / (1.0f + __expf(-v1));
            float v2 = acc[n][2] + b1c[n]; v2 = v2 / (1.0f + __expf(-v2));
            float v3 = acc[n][3] + b1c[n]; v3 = v3 / (1.0f + __expf(-v3));
            pv0 += v0 * w2c[n]; pv1 += v1 * w2c[n];
            pv2 += v2 * w2c[n]; pv3 += v3 * w2c[n];
        }
#pragma unroll
        for (int sh = 1; sh <= 8; sh <<= 1) {
            pv0 += __shfl_xor(pv0, sh, 64);
            pv1 += __shfl_xor(pv1, sh, 64);
            pv2 += __shfl_xor(pv2, sh, 64);
            pv3 += __shfl_xor(pv3, sh, 64);
        }
        float val = (am == 0) ? pv0 : (am == 1) ? pv1 : (am == 2) ? pv2 : pv3;
        int tgt = __shfl(gidC, g * 4 + am, 64);
        if (am < 4 && g * 4 + am < rowsC) out[tgt] = val + b2v;

        rowsC = rowsN; gidC = gidN;
        if (s + 2 < s1) { rowsN = ROWSOF(s + 2); gidN = GIDOF(s + 2); }
    }
#undef ROWSOF
#undef GIDOF
}

// ---------------- launch -------------------------------------------------------
extern "C" void kernel_launch(void* const* d_in, const int* in_sizes, int n_in,
                              void* d_out, int out_size, void* d_ws, size_t ws_size,
                              hipStream_t stream) {
    const int*   z  = (const int*)  d_in[0];
    const float* X  = (const float*)d_in[1];
    const float* W1 = (const float*)d_in[2];
    const float* B1 = (const float*)d_in[3];
    const float* W2 = (const float*)d_in[4];
    const float* B2 = (const float*)d_in[5];
    float* out = (float*)d_out;
    int nAtoms = in_sizes[0];

    char* ws = (char*)d_ws;
    size_t off = 0;
    char* W1s     = ws + off;          off += (size_t)N_ELEM * ESTRIDE;  // 332800
    int* perm     = (int*)(ws + off);  off += (size_t)nAtoms * 4;
    int* counts   = (int*)(ws + off);  off += 32;
    int* blockCnt = (int*)(ws + off);  off += (size_t)PREPB * N_ELEM * 4;

    void* args[] = {(void*)&W1, (void*)&B1, (void*)&W2, (void*)&W1s,
                    (void*)&z, (void*)&nAtoms, (void*)&blockCnt,
                    (void*)&counts, (void*)&perm};
    hipLaunchCooperativeKernel((const void*)coop_prep_kernel,
                               dim3(PREPB), dim3(256), args, 0, stream);

    mlp_kernel<<<NBLK, 256, 0, stream>>>(X, W1s, B2, perm, counts, out);
}

// Round 17
// 57.629 us; speedup vs baseline: 1.4798x; 1.4798x over previous
//
#include <hip/hip_runtime.h>
#include <hip/hip_bf16.h>

#define N_IN    256
#define N_HID   128
#define N_ELEM  5
#define NBLK    512                 // mlp blocks; 2 per CU (65.5KB LDS each)
#define ESTRIDE 66560               // per-expert image: 65536 frag + 1024 params

typedef __attribute__((ext_vector_type(8))) short  short8;
typedef __attribute__((ext_vector_type(4))) short  short4v;
typedef __attribute__((ext_vector_type(4))) float  float4v;

__device__ __forceinline__ int expert_of(int z) {
    return (z == 1) ? 0 : (z == 6) ? 1 : (z == 7) ? 2 : (z == 8) ? 3 : 4;
}
__device__ __forceinline__ short f2bf(float f) {
    union { float f; unsigned u; } c; c.f = f;
    unsigned r = (c.u + 0x7fffu + ((c.u >> 16) & 1u)) >> 16;
    return (short)r;
}

#define AS3 __attribute__((address_space(3)))
#define GLOAD_LDS16(gsrc, ldst) \
    __builtin_amdgcn_global_load_lds((const __attribute__((address_space(1))) void*)(gsrc), \
                                     (AS3 void*)(ldst), 16, 0, 0)
__device__ __forceinline__ unsigned lds_off(const void* p) {
    return (unsigned)(size_t)(AS3 const char*)p;
}

#define DSR128(dst, a) asm volatile("ds_read_b128 %0, %1" : "=v"(dst) : "v"(a))
#define LGKM0 do { asm volatile("s_waitcnt lgkmcnt(0)" ::: "memory"); \
                   __builtin_amdgcn_sched_barrier(0); } while (0)
#define WAITV0 do { asm volatile("s_waitcnt vmcnt(0)" ::: "memory"); \
                    __builtin_amdgcn_sched_barrier(0); } while (0)

// ---------------- prep: W1s image (85 blocks) + per-block counts (no atomics) --
__global__ void prep_hist_kernel(const float* __restrict__ W1, const float* __restrict__ B1f,
                                 const float* __restrict__ W2f, char* __restrict__ W1s,
                                 const int* __restrict__ z, int n,
                                 int* __restrict__ blockCnt) {
    if (blockIdx.x < 85) {
        int idx = blockIdx.x * 256 + threadIdx.x;
        if (idx < 20480) {
            int e = idx >> 12, rem = idx & 4095;
            int slot = rem >> 6, lane = rem & 63;
            int nrow = (slot >> 3) * 16 + (lane & 15);
            int k0 = (slot & 7) * 32 + (lane >> 4) * 8;
            const float* src = W1 + ((size_t)(e * N_HID + nrow) * N_IN + k0);
            float4v f0 = *(const float4v*)src;
            float4v f1 = *(const float4v*)(src + 4);
            short8 s;
            s[0] = f2bf(f0[0]); s[1] = f2bf(f0[1]); s[2] = f2bf(f0[2]); s[3] = f2bf(f0[3]);
            s[4] = f2bf(f1[0]); s[5] = f2bf(f1[1]); s[6] = f2bf(f1[2]); s[7] = f2bf(f1[3]);
            *(short8*)(W1s + (size_t)e * ESTRIDE + slot * 1024 + lane * 16) = s;
        } else if (idx < 21760) {
            int idx2 = idx - 20480;              // < 1280
            int e = idx2 >> 8, i = idx2 & 255;
            float* dst = (float*)(W1s + (size_t)e * ESTRIDE + 65536);
            if (i < 128) dst[i] = B1f[e * N_HID + i];
            else         dst[128 + (i - 128)] = W2f[e * N_HID + (i - 128)];
        }
        return;
    }
    __shared__ int wcnt[4][N_ELEM];
    int b = blockIdx.x - 85;
    int tid = threadIdx.x, w = tid >> 6, lane = tid & 63;
    int a = b * 256 + tid;
    int e = (a < n) ? expert_of(z[a]) : -1;
#pragma unroll
    for (int ex = 0; ex < N_ELEM; ++ex) {
        unsigned long long m = __ballot(e == ex);
        if (lane == 0) wcnt[w][ex] = __popcll(m);
    }
    __syncthreads();
    if (tid < N_ELEM)
        blockCnt[b * N_ELEM + tid] =
            wcnt[0][tid] + wcnt[1][tid] + wcnt[2][tid] + wcnt[3][tid];
}

// ---------------- scatter: ballot-ordered ranks + prefix from blockCnt --------
// perm is strictly ascending (by original index) within each expert, and fully
// deterministic. Block 0 also writes counts[5] for the mlp kernel.
__global__ void scatter_kernel(const int* __restrict__ z, int n, int nb,
                               const int* __restrict__ blockCnt,
                               int* __restrict__ counts, int* __restrict__ perm) {
    __shared__ int wcnt[4][N_ELEM], wbase[4][N_ELEM];
    __shared__ int redT[4][N_ELEM], redB[4][N_ELEM];
    __shared__ int blockBase[N_ELEM];

    int tid = threadIdx.x, b = blockIdx.x;
    int w = tid >> 6, lane = tid & 63;
    int a = b * 256 + tid;
    int e = (a < n) ? expert_of(z[a]) : -1;

    // ordered rank within wave / block
    int rankInWave = 0;
#pragma unroll
    for (int ex = 0; ex < N_ELEM; ++ex) {
        unsigned long long m = __ballot(e == ex);
        if (e == ex) rankInWave = __popcll(m & ((1ull << lane) - 1ull));
        if (lane == 0) wcnt[w][ex] = __popcll(m);
    }
    __syncthreads();
    if (tid < N_ELEM) {
        int s = 0;
#pragma unroll
        for (int ww = 0; ww < 4; ++ww) { wbase[ww][tid] = s; s += wcnt[ww][tid]; }
    }

    // global prefix: totals + mass in blocks below ours (L2-resident scan)
    int tot[N_ELEM] = {}, below[N_ELEM] = {};
    for (int idx = tid; idx < nb; idx += 256) {
        int isb = (idx < b);
#pragma unroll
        for (int ex = 0; ex < N_ELEM; ++ex) {
            int v = blockCnt[idx * N_ELEM + ex];
            tot[ex] += v;
            below[ex] += isb ? v : 0;
        }
    }
#pragma unroll
    for (int ex = 0; ex < N_ELEM; ++ex) {
#pragma unroll
        for (int sh = 1; sh <= 32; sh <<= 1) {
            tot[ex]   += __shfl_xor(tot[ex], sh, 64);
            below[ex] += __shfl_xor(below[ex], sh, 64);
        }
        if (lane == 0) { redT[w][ex] = tot[ex]; redB[w][ex] = below[ex]; }
    }
    __syncthreads();
    if (tid == 0) {
        int seg = 0;
#pragma unroll
        for (int ex = 0; ex < N_ELEM; ++ex) {
            int T  = redT[0][ex] + redT[1][ex] + redT[2][ex] + redT[3][ex];
            int Bl = redB[0][ex] + redB[1][ex] + redB[2][ex] + redB[3][ex];
            blockBase[ex] = seg + Bl;
            if (b == 0) counts[ex] = T;
            seg += T;
        }
    }
    __syncthreads();
    if (e >= 0) perm[blockBase[e] + wbase[w][e] + rankInWave] = a;
}

// ---------------- mlp: expert-uniform blocks, shared 64KB B, interleaved pipe --
// (byte-identical to R15's passing 72.0us kernel)
__launch_bounds__(256, 2)
__global__ void mlp_kernel(const float* __restrict__ X, const char* __restrict__ W1s,
                           const float* __restrict__ B2f, const int* __restrict__ perm,
                           const int* __restrict__ counts, float* __restrict__ out) {
    __shared__ char Bs[65536];              // one expert's full fragment image

    int lane = threadIdx.x & 63;
    int w    = threadIdx.x >> 6;
    int am   = lane & 15, g = lane >> 4;

    int cntv[N_ELEM], so[N_ELEM], ns[N_ELEM];
    int nSub = 0, acc0 = 0;
#pragma unroll
    for (int e = 0; e < N_ELEM; ++e) {
        cntv[e] = counts[e];
        so[e] = acc0; acc0 += cntv[e];
        ns[e] = (cntv[e] + 15) >> 4;
        nSub += ns[e];
    }
    int blk[N_ELEM], tot = 0;
#pragma unroll
    for (int e = 0; e < N_ELEM; ++e) {
        blk[e] = (int)(((long long)NBLK * ns[e]) / nSub);
        tot += blk[e];
    }
    int rem = NBLK - tot;
#pragma unroll
    for (int e = 0; e < N_ELEM; ++e)
        if (rem > 0 && ns[e] > 0) { blk[e]++; rem--; }
    while (rem > 0) { blk[0]++; rem--; }
#pragma unroll
    for (int e = 0; e < N_ELEM; ++e)
        if (ns[e] > 0 && blk[e] == 0) {
            int m = 0;
            for (int j = 1; j < N_ELEM; ++j) if (blk[j] > blk[m]) m = j;
            blk[m]--; blk[e]++;
        }
    int bp1 = blk[0], bp2 = bp1 + blk[1], bp3 = bp2 + blk[2], bp4 = bp3 + blk[3];

    int b = blockIdx.x;
    int e = (b >= bp1) + (b >= bp2) + (b >= bp3) + (b >= bp4);
    int bloc = b - ((e == 0) ? 0 : (e == 1) ? bp1 : (e == 2) ? bp2 : (e == 3) ? bp3 : bp4);
    int BE = blk[e], NE = ns[e];
    int soE = so[e], ctE = cntv[e];

    const char* img = W1s + (size_t)e * ESTRIDE;
    {
        const char* wsrc = img + w * 16384 + lane * 16;
        char* wdst = Bs + w * 16384;
#pragma unroll
        for (int i = 0; i < 16; ++i)
            GLOAD_LDS16(wsrc + i * 1024, wdst + i * 1024);
    }
    WAITV0;
    __syncthreads();

    int qe = (BE > 0) ? NE / BE : 0, re = (BE > 0) ? NE % BE : 0;
    int tb0 = bloc * qe + min(bloc, re);
    int tb1 = tb0 + qe + (bloc < re ? 1 : 0);
    int L = tb1 - tb0;
    int qw = L >> 2, rw = L & 3;
    int s0 = tb0 + w * qw + min(w, rw);
    int s1 = s0 + qw + (w < rw ? 1 : 0);
    if (s0 >= s1) return;

    unsigned BOFF = lds_off(Bs);
    int lastA = soE + ctE - 1;

    const float* prm = (const float*)(img + 65536);
    float b1c[8], w2c[8];
#pragma unroll
    for (int n = 0; n < 8; ++n) {
        b1c[n] = prm[n * 16 + am];
        w2c[n] = prm[128 + n * 16 + am];
    }
    float b2v = B2f[e];

#define ROWSOF(s_) min(16, ctE - (s_) * 16)
#define GIDOF(s_) perm[min(soE + (s_) * 16 + am, lastA)]

    int rowsC = ROWSOF(s0);
    int gidC = GIDOF(s0);
    float4v rawA[16];
    {
        const float* base0 = X + ((size_t)(unsigned)gidC << 8) + g * 8;
#pragma unroll
        for (int kk = 0; kk < 8; ++kk) {
            rawA[2 * kk]     = *(const float4v*)(base0 + kk * 32);
            rawA[2 * kk + 1] = *(const float4v*)(base0 + kk * 32 + 4);
        }
    }
    int rowsN = rowsC, gidN = gidC;
    if (s0 + 1 < s1) { rowsN = ROWSOF(s0 + 1); gidN = GIDOF(s0 + 1); }

    for (int s = s0; s < s1; ++s) {
        bool pf = (s + 1 < s1);
        const float* baseN = X + ((size_t)(unsigned)gidN << 8) + g * 8;

        float4v acc[8] = {};
#pragma unroll
        for (int kk = 0; kk < 8; ++kk) {
            short8 bpre[8];
#pragma unroll
            for (int n = 0; n < 8; ++n)
                DSR128(bpre[n], BOFF + (unsigned)((n * 8 + kk) * 1024 + lane * 16));
            short8 abf;
            {
                float4v f0 = rawA[2 * kk], f1 = rawA[2 * kk + 1];
                union { __hip_bfloat162 h[4]; short8 v; } u;
                u.h[0] = __float22bfloat162_rn({f0[0], f0[1]});
                u.h[1] = __float22bfloat162_rn({f0[2], f0[3]});
                u.h[2] = __float22bfloat162_rn({f1[0], f1[1]});
                u.h[3] = __float22bfloat162_rn({f1[2], f1[3]});
                abf = u.v;
            }
            if (pf) {
                rawA[2 * kk]     = *(const float4v*)(baseN + kk * 32);
                rawA[2 * kk + 1] = *(const float4v*)(baseN + kk * 32 + 4);
            }
            LGKM0;
#pragma unroll
            for (int n = 0; n < 8; ++n)
                acc[n] = __builtin_amdgcn_mfma_f32_16x16x32_bf16(
                    abf, bpre[n], acc[n], 0, 0, 0);
        }

        float pv0 = 0, pv1 = 0, pv2 = 0, pv3 = 0;
#pragma unroll
        for (int n = 0; n < 8; ++n) {
            float v0 = acc[n][0] + b1c[n]; v0 = v0 / (1.0f + __expf(-v0));
            float v1 = acc[n][1] + b1c[n]; v1 = v1 / (1.0f + __expf(-v1));
            float v2 = acc[n][2] + b1c[n]; v2 = v2 / (1.0f + __expf(-v2));
            float v3 = acc[n][3] + b1c[n]; v3 = v3 / (1.0f + __expf(-v3));
            pv0 += v0 * w2c[n]; pv1 += v1 * w2c[n];
            pv2 += v2 * w2c[n]; pv3 += v3 * w2c[n];
        }
#pragma unroll
        for (int sh = 1; sh <= 8; sh <<= 1) {
            pv0 += __shfl_xor(pv0, sh, 64);
            pv1 += __shfl_xor(pv1, sh, 64);
            pv2 += __shfl_xor(pv2, sh, 64);
            pv3 += __shfl_xor(pv3, sh, 64);
        }
        float val = (am == 0) ? pv0 : (am == 1) ? pv1 : (am == 2) ? pv2 : pv3;
        int tgt = __shfl(gidC, g * 4 + am, 64);
        if (am < 4 && g * 4 + am < rowsC) out[tgt] = val + b2v;

        rowsC = rowsN; gidC = gidN;
        if (s + 2 < s1) { rowsN = ROWSOF(s + 2); gidN = GIDOF(s + 2); }
    }
#undef ROWSOF
#undef GIDOF
}

// ---------------- launch -------------------------------------------------------
extern "C" void kernel_launch(void* const* d_in, const int* in_sizes, int n_in,
                              void* d_out, int out_size, void* d_ws, size_t ws_size,
                              hipStream_t stream) {
    const int*   z  = (const int*)  d_in[0];
    const float* X  = (const float*)d_in[1];
    const float* W1 = (const float*)d_in[2];
    const float* B1 = (const float*)d_in[3];
    const float* W2 = (const float*)d_in[4];
    const float* B2 = (const float*)d_in[5];
    float* out = (float*)d_out;
    int nAtoms = in_sizes[0];

    int hb = (nAtoms + 255) / 256;

    char* ws = (char*)d_ws;
    size_t off = 0;
    char* W1s     = ws + off;          off += (size_t)N_ELEM * ESTRIDE;  // 332800
    int* perm     = (int*)(ws + off);  off += (size_t)nAtoms * 4;
    int* counts   = (int*)(ws + off);  off += 32;
    int* blockCnt = (int*)(ws + off);  off += (size_t)hb * N_ELEM * 4;

    prep_hist_kernel<<<85 + hb, 256, 0, stream>>>(W1, B1, W2, W1s, z, nAtoms, blockCnt);
    scatter_kernel<<<hb, 256, 0, stream>>>(z, nAtoms, hb, blockCnt, counts, perm);
    mlp_kernel<<<NBLK, 256, 0, stream>>>(X, W1s, B2, perm, counts, out);
}